// Round 1
// baseline (962.617 us; speedup 1.0000x reference)
//
#include <hip/hip_runtime.h>
#include <math.h>

// TopKGate: logits = x @ W^T ; softmax ; top-2 ; scatter weights + indices.
// x: [8192, 4096] f32, W: [64, 4096] f32.
// d_out (f32 flat): weights [8192*64] then top_i [8192*2] written as floats.

#define TOKENS 8192
#define DIM    4096
#define NEXP   64
#define TB     16              // tokens per block
#define WAVES  8               // k-split across the 8 waves of the block
#define THREADS (WAVES * 64)   // 512
#define KSEG   (DIM / WAVES)   // 512 k's per wave
#define KC     64              // k-chunk held in VGPRs per refill

__global__ __launch_bounds__(THREADS, 4)
void topk_gate_kernel(const float* __restrict__ x,
                      const float* __restrict__ W,
                      float* __restrict__ out_w,
                      float* __restrict__ out_i)
{
    // per-wave partial logits for deterministic cross-wave reduction: 32 KB
    __shared__ float part[WAVES * TB * NEXP];

    const int tid  = threadIdx.x;
    const int lane = tid & 63;          // lane = expert index
    const int wave = tid >> 6;          // wave = k-segment index
    const int tok0 = blockIdx.x * TB;

    float acc[TB];
#pragma unroll
    for (int t = 0; t < TB; ++t) acc[t] = 0.0f;

    const int kbase = wave * KSEG;
    const float* Wrow  = W + (size_t)lane * DIM + kbase;  // per-lane expert row
    const float* xbase = x + (size_t)tok0 * DIM + kbase;  // wave-uniform

    for (int kc = 0; kc < KSEG; kc += KC) {
        // refill W chunk into VGPRs: 16 x float4 per lane (lane-strided, L2-hot)
        float4 wv[KC / 4];
#pragma unroll
        for (int i = 0; i < KC / 4; ++i)
            wv[i] = *reinterpret_cast<const float4*>(Wrow + kc + 4 * i);

        // x loads are wave-uniform -> scalar loads; FMA uses SGPR broadcast
#pragma unroll
        for (int t = 0; t < TB; ++t) {
            const float* xrow = xbase + (size_t)t * DIM + kc;
            float s0 = 0.f, s1 = 0.f, s2 = 0.f, s3 = 0.f;
#pragma unroll
            for (int i = 0; i < KC / 4; ++i) {
                const float4 xv = *reinterpret_cast<const float4*>(xrow + 4 * i);
                s0 = fmaf(xv.x, wv[i].x, s0);
                s1 = fmaf(xv.y, wv[i].y, s1);
                s2 = fmaf(xv.z, wv[i].z, s2);
                s3 = fmaf(xv.w, wv[i].w, s3);
            }
            acc[t] += (s0 + s1) + (s2 + s3);
        }
    }

    // ---- deterministic cross-wave reduction (no float atomics) ----
#pragma unroll
    for (int t = 0; t < TB; ++t)
        part[(wave * TB + t) * NEXP + lane] = acc[t];  // lane-consecutive: conflict-free
    __syncthreads();

    for (int idx = tid; idx < TB * NEXP; idx += THREADS) {
        float s = 0.f;
#pragma unroll
        for (int w = 0; w < WAVES; ++w)
            s += part[w * TB * NEXP + idx];
        part[idx] = s;  // each idx owned by exactly one thread; no race
    }
    __syncthreads();

    const float* slog = part;  // logits[TB][NEXP]

    // ---- epilogue: softmax + top-2, one token per wave-iteration ----
#pragma unroll
    for (int tt = 0; tt < TB / WAVES; ++tt) {
        const int t = wave * (TB / WAVES) + tt;
        const float v = slog[t * NEXP + lane];

        float m = v;
        for (int o = 32; o > 0; o >>= 1)
            m = fmaxf(m, __shfl_xor(m, o));
        const float p = expf(v - m);
        float s = p;
        for (int o = 32; o > 0; o >>= 1)
            s += __shfl_xor(s, o);
        const float prob = p / s;

        // top-1: larger value wins; on tie, lower index wins (jax top_k order)
        float v1 = prob; int i1 = lane;
        for (int o = 32; o > 0; o >>= 1) {
            const float ov = __shfl_xor(v1, o);
            const int   oi = __shfl_xor(i1, o);
            if (ov > v1 || (ov == v1 && oi < i1)) { v1 = ov; i1 = oi; }
        }
        // top-2: mask out winner (probs >= 0 > -1)
        float v2 = (lane == i1) ? -1.0f : prob;
        int   i2 = lane;
        for (int o = 32; o > 0; o >>= 1) {
            const float ov = __shfl_xor(v2, o);
            const int   oi = __shfl_xor(i2, o);
            if (ov > v2 || (ov == v2 && oi < i2)) { v2 = ov; i2 = oi; }
        }

        const int gt = tok0 + t;
        out_w[(size_t)gt * NEXP + lane] =
            (lane == i1) ? v1 : ((lane == i2) ? v2 : 0.0f);
        if (lane == 0) {
            out_i[(size_t)gt * 2 + 0] = (float)i1;
            out_i[(size_t)gt * 2 + 1] = (float)i2;
        }
    }
}

extern "C" void kernel_launch(void* const* d_in, const int* in_sizes, int n_in,
                              void* d_out, int out_size, void* d_ws, size_t ws_size,
                              hipStream_t stream) {
    const float* x = (const float*)d_in[0];
    const float* W = (const float*)d_in[1];
    float* out_w = (float*)d_out;
    float* out_i = out_w + (size_t)TOKENS * NEXP;
    topk_gate_kernel<<<dim3(TOKENS / TB), dim3(THREADS), 0, stream>>>(x, W, out_w, out_i);
}

// Round 2
// 269.857 us; speedup vs baseline: 3.5671x; 3.5671x over previous
//
#include <hip/hip_runtime.h>
#include <math.h>

// TopKGate: logits = x @ W^T ; softmax ; top-2 ; scatter weights + indices(float).
// x: [8192,4096] f32, W: [64,4096] f32.
// d_out (f32 flat): weights [8192*64] then indices [8192*2] as floats.

#define TOKENS 8192
#define DIM    4096
#define NEXP   64

#define MWAVES 16          // waves per main block
#define KHALF  2           // k-split across blocks
#define KSEG   (DIM / KHALF / MWAVES)   // 128 k per wave
#define KC     16          // k chunk staged in LDS
#define NCHUNK (KSEG / KC) // 8
#define SLABW  (KC + 1)    // 17 floats per slab row (bank-conflict-free)

// ---------- kernel 1: W[64][4096] -> Wt[4096][64] ----------
__global__ void tg_wt(const float* __restrict__ W, float* __restrict__ Wt) {
    int gid = blockIdx.x * blockDim.x + threadIdx.x;  // 65536 = 4096 * 16
    int k  = gid >> 4;
    int eq = gid & 15;
    float4 v;
    v.x = W[(size_t)(eq * 4 + 0) * DIM + k];
    v.y = W[(size_t)(eq * 4 + 1) * DIM + k];
    v.z = W[(size_t)(eq * 4 + 2) * DIM + k];
    v.w = W[(size_t)(eq * 4 + 3) * DIM + k];
    *reinterpret_cast<float4*>(Wt + (size_t)k * NEXP + eq * 4) = v;
}

// ---------- kernel 2: main GEMM, partial logits ----------
__global__ __launch_bounds__(1024, 4)
void tg_main(const float* __restrict__ x, const float* __restrict__ Wt,
             float* __restrict__ part)
{
    // 16 wave-private slabs (64*17 floats each) = 69632 B; reused as 4 reduce
    // buffers of 4096 floats (16384 floats needed <= 17408 available).
    __shared__ float lds[MWAVES * 64 * SLABW];

    const int tid   = threadIdx.x;
    const int lane  = tid & 63;
    const int wave  = tid >> 6;
    const int tg    = blockIdx.x >> 1;      // 0..127
    const int khalf = blockIdx.x & 1;
    const int k0w   = khalf * (DIM / 2) + wave * KSEG;

    float acc[NEXP];
#pragma unroll
    for (int e = 0; e < NEXP; ++e) acc[e] = 0.0f;

    float* slab = lds + wave * 64 * SLABW;
    const int srow = lane >> 2;        // 0..15
    const int scol = (lane & 3) * 4;   // 0,4,8,12
    const float* xg = x + (size_t)(tg * 64) * DIM + k0w;

    // prefetch chunk 0 into registers
    float4 pre[4];
#pragma unroll
    for (int i = 0; i < 4; ++i)
        pre[i] = *reinterpret_cast<const float4*>(xg + (size_t)(16 * i + srow) * DIM + scol);

    for (int c = 0; c < NCHUNK; ++c) {
        // write prefetched chunk into slab (wave-private: no barrier needed)
#pragma unroll
        for (int i = 0; i < 4; ++i) {
            float* dst = slab + (16 * i + srow) * SLABW + scol;
            dst[0] = pre[i].x; dst[1] = pre[i].y; dst[2] = pre[i].z; dst[3] = pre[i].w;
        }
        // issue next chunk's global loads (overlap with compute below)
        if (c + 1 < NCHUNK) {
#pragma unroll
            for (int i = 0; i < 4; ++i)
                pre[i] = *reinterpret_cast<const float4*>(
                    xg + (size_t)(16 * i + srow) * DIM + (c + 1) * KC + scol);
        }
        // compute: per k, x from LDS (2-way free), W row wave-uniform -> s_load
        const float* wbase = Wt + (size_t)(k0w + c * KC) * NEXP;
        const float* xrow  = slab + lane * SLABW;
#pragma unroll 2
        for (int kk = 0; kk < KC; ++kk) {
            float xv = xrow[kk];
            const float* wrow = wbase + kk * NEXP;
#pragma unroll
            for (int e = 0; e < NEXP; ++e)
                acc[e] = fmaf(wrow[e], xv, acc[e]);
        }
    }

    // ---- deterministic 16-wave tree reduction over LDS ----
    // buffer layout: buf[lane][e] with 16B-chunk XOR-rotate swizzle
    float* buf0 = lds;
    auto dump = [&](int b) {
        float* buf = buf0 + b * 4096;
#pragma unroll
        for (int cc = 0; cc < 16; ++cc) {
            float4 v = make_float4(acc[4*cc], acc[4*cc+1], acc[4*cc+2], acc[4*cc+3]);
            *reinterpret_cast<float4*>(buf + lane * 64 + (((cc + lane) & 15) << 2)) = v;
        }
    };
    auto fold = [&](int b) {
        float* buf = buf0 + b * 4096;
#pragma unroll
        for (int cc = 0; cc < 16; ++cc) {
            float4 v = *reinterpret_cast<const float4*>(buf + lane * 64 + (((cc + lane) & 15) << 2));
            acc[4*cc] += v.x; acc[4*cc+1] += v.y; acc[4*cc+2] += v.z; acc[4*cc+3] += v.w;
        }
    };

    __syncthreads();
    if (wave >= 8 && wave < 12) dump(wave - 8);
    __syncthreads();
    if (wave < 4) fold(wave);
    __syncthreads();
    if (wave >= 12) dump(wave - 12);
    __syncthreads();
    if (wave >= 4 && wave < 8) fold(wave - 4);
    __syncthreads();
    if (wave >= 4 && wave < 8) dump(wave - 4);
    __syncthreads();
    if (wave < 4) fold(wave);
    __syncthreads();
    if (wave >= 2 && wave < 4) dump(wave - 2);
    __syncthreads();
    if (wave < 2) fold(wave);
    __syncthreads();
    if (wave == 1) dump(0);
    __syncthreads();
    if (wave == 0) {
        fold(0);
        float* dst = part + ((size_t)(tg * 2 + khalf) * 64 + lane) * NEXP;
#pragma unroll
        for (int cc = 0; cc < 16; ++cc)
            *reinterpret_cast<float4*>(dst + 4 * cc) =
                make_float4(acc[4*cc], acc[4*cc+1], acc[4*cc+2], acc[4*cc+3]);
    }
}

// ---------- kernel 3: combine halves, softmax, top-2, scatter ----------
__global__ void tg_final(const float* __restrict__ part,
                         float* __restrict__ out_w, float* __restrict__ out_i)
{
    int t  = blockIdx.x * blockDim.x + threadIdx.x;  // 0..8191
    int tg = t >> 6, l = t & 63;
    const float* p0 = part + ((size_t)(tg * 2 + 0) * 64 + l) * NEXP;
    const float* p1 = part + ((size_t)(tg * 2 + 1) * 64 + l) * NEXP;

    float lg[NEXP];
    float m = -1e30f;
#pragma unroll
    for (int e = 0; e < NEXP; e += 4) {
        float4 a = *reinterpret_cast<const float4*>(p0 + e);
        float4 b = *reinterpret_cast<const float4*>(p1 + e);
        lg[e+0] = a.x + b.x; lg[e+1] = a.y + b.y;
        lg[e+2] = a.z + b.z; lg[e+3] = a.w + b.w;
        m = fmaxf(m, fmaxf(fmaxf(lg[e+0], lg[e+1]), fmaxf(lg[e+2], lg[e+3])));
    }
    float s = 0.0f;
#pragma unroll
    for (int e = 0; e < NEXP; ++e) { lg[e] = expf(lg[e] - m); s += lg[e]; }
    float inv = 1.0f / s;

    // top-2 on probs; ascending scan + strict '>' => lower index wins ties
    float v1 = -1.0f, v2 = -1.0f; int i1 = 0, i2 = 0;
#pragma unroll
    for (int e = 0; e < NEXP; ++e) {
        float p = lg[e] * inv;
        lg[e] = p;
        if (p > v1)      { v2 = v1; i2 = i1; v1 = p; i1 = e; }
        else if (p > v2) { v2 = p; i2 = e; }
    }

    float* dst = out_w + (size_t)t * NEXP;
#pragma unroll
    for (int e = 0; e < NEXP; e += 4) {
        float4 o;
        o.x = (e+0 == i1) ? v1 : (e+0 == i2) ? v2 : 0.0f;
        o.y = (e+1 == i1) ? v1 : (e+1 == i2) ? v2 : 0.0f;
        o.z = (e+2 == i1) ? v1 : (e+2 == i2) ? v2 : 0.0f;
        o.w = (e+3 == i1) ? v1 : (e+3 == i2) ? v2 : 0.0f;
        *reinterpret_cast<float4*>(dst + e) = o;
    }
    out_i[(size_t)t * 2 + 0] = (float)i1;
    out_i[(size_t)t * 2 + 1] = (float)i2;
}

extern "C" void kernel_launch(void* const* d_in, const int* in_sizes, int n_in,
                              void* d_out, int out_size, void* d_ws, size_t ws_size,
                              hipStream_t stream) {
    const float* x = (const float*)d_in[0];
    const float* W = (const float*)d_in[1];
    float* out_w = (float*)d_out;
    float* out_i = out_w + (size_t)TOKENS * NEXP;

    float* part = (float*)d_ws;                         // 256 * 64 * 64 f32 = 4 MB
    float* Wt   = part + (size_t)256 * 64 * NEXP;       // 4096 * 64 f32 = 1 MB

    tg_wt   <<<dim3(256), dim3(256), 0, stream>>>(W, Wt);
    tg_main <<<dim3(256), dim3(1024), 0, stream>>>(x, Wt, part);
    tg_final<<<dim3(TOKENS / 256), dim3(256), 0, stream>>>(part, out_w, out_i);
}

// Round 3
// 115.452 us; speedup vs baseline: 8.3378x; 2.3374x over previous
//
#include <hip/hip_runtime.h>
#include <math.h>

// TopKGate: logits = x @ W^T ; softmax ; top-2 ; scatter weights + indices(float).
// x: [8192,4096] f32, W: [64,4096] f32.
// d_out (f32 flat): weights [8192*64] then indices [8192*2] as floats.
//
// Layout: lane = expert (W chunk in VGPRs), x = wave-uniform broadcast loads.
// k split 2x across blocks, 8x across waves; LDS tree-reduce; tiny finalize.

#define TOKENS 8192
#define DIM    4096
#define NEXP   64

#define TBLK   32                    // tokens per block
#define BWAVES 8                     // waves per block
#define KB     2                     // k-split across blocks
#define KSEG   (DIM / KB / BWAVES)   // 256 k per wave
#define KC     32                    // W chunk held in VGPRs
#define NCH    (KSEG / KC)           // 8 chunks

__global__ __launch_bounds__(512, 4)
void tg_main(const float* __restrict__ x, const float* __restrict__ W,
             float* __restrict__ part)
{
    __shared__ float rbuf[4][TBLK * NEXP];   // 4 x 8 KB reduce buffers

    const int tid  = threadIdx.x;
    const int lane = tid & 63;                                   // = expert
    const int wave = __builtin_amdgcn_readfirstlane(tid >> 6);   // uniform!
    const int tg   = blockIdx.x >> 1;        // token group 0..255
    const int kb   = blockIdx.x & 1;         // k half
    const int tok0 = tg * TBLK;
    const int k0   = kb * (DIM / KB) + wave * KSEG;

    float acc[TBLK];
#pragma unroll
    for (int t = 0; t < TBLK; ++t) acc[t] = 0.0f;

    const float* wrow  = W + (size_t)lane * DIM + k0;   // per-lane expert row
    const float* xbase = x + (size_t)tok0 * DIM + k0;   // wave-uniform

    for (int c = 0; c < NCH; ++c) {
        // refill W chunk into VGPRs (lane-strided rows; W is L2-resident)
        float4 wv[KC / 4];
#pragma unroll
        for (int i = 0; i < KC / 4; ++i)
            wv[i] = *reinterpret_cast<const float4*>(wrow + c * KC + 4 * i);

        // x loads are wave-uniform (broadcast / s_load); each feeds 4 FMAs
#pragma unroll 8
        for (int t = 0; t < TBLK; ++t) {
            const float* xr = xbase + (size_t)t * DIM + c * KC;
#pragma unroll
            for (int q = 0; q < KC / 4; ++q) {
                const float4 xv = *reinterpret_cast<const float4*>(xr + 4 * q);
                acc[t] = fmaf(xv.x, wv[q].x, acc[t]);
                acc[t] = fmaf(xv.y, wv[q].y, acc[t]);
                acc[t] = fmaf(xv.z, wv[q].z, acc[t]);
                acc[t] = fmaf(xv.w, wv[q].w, acc[t]);
            }
        }
    }

    // ---- deterministic 8-wave tree reduction (8 -> 4 -> 2 -> 1) ----
    // dump/fold access: fixed t, lanes hit banks 0..31 twice = 2-way = free
    auto dump = [&](int b) {
        float* buf = &rbuf[b][0];
#pragma unroll
        for (int t = 0; t < TBLK; ++t) buf[t * NEXP + lane] = acc[t];
    };
    auto fold = [&](int b) {
        const float* buf = &rbuf[b][0];
#pragma unroll
        for (int t = 0; t < TBLK; ++t) acc[t] += buf[t * NEXP + lane];
    };

    if (wave >= 4) dump(wave - 4);
    __syncthreads();
    if (wave < 4) fold(wave);
    __syncthreads();
    if (wave == 2 || wave == 3) dump(wave - 2);
    __syncthreads();
    if (wave < 2) fold(wave);
    __syncthreads();
    if (wave == 1) dump(0);
    __syncthreads();
    if (wave == 0) {
        fold(0);
        float* dst = part + ((size_t)kb * TOKENS + tok0) * NEXP;
#pragma unroll
        for (int t = 0; t < TBLK; ++t) dst[t * NEXP + lane] = acc[t];
    }
}

// ---------- finalize: combine k-halves, softmax, top-2, scatter ----------
__global__ void tg_final(const float* __restrict__ part,
                         float* __restrict__ out_w, float* __restrict__ out_i)
{
    int t = blockIdx.x * blockDim.x + threadIdx.x;   // 0..8191
    const float* p0 = part + (size_t)t * NEXP;
    const float* p1 = part + (size_t)(TOKENS + t) * NEXP;

    float lg[NEXP];
    float m = -1e30f;
#pragma unroll
    for (int e = 0; e < NEXP; e += 4) {
        float4 a = *reinterpret_cast<const float4*>(p0 + e);
        float4 b = *reinterpret_cast<const float4*>(p1 + e);
        lg[e+0] = a.x + b.x; lg[e+1] = a.y + b.y;
        lg[e+2] = a.z + b.z; lg[e+3] = a.w + b.w;
        m = fmaxf(m, fmaxf(fmaxf(lg[e+0], lg[e+1]), fmaxf(lg[e+2], lg[e+3])));
    }
    float s = 0.0f;
#pragma unroll
    for (int e = 0; e < NEXP; ++e) { lg[e] = expf(lg[e] - m); s += lg[e]; }
    float inv = 1.0f / s;

    // top-2 on probs; strict '>' scan => lower index wins ties (jax order)
    float v1 = -1.0f, v2 = -1.0f; int i1 = 0, i2 = 0;
#pragma unroll
    for (int e = 0; e < NEXP; ++e) {
        float p = lg[e] * inv;
        lg[e] = p;
        if (p > v1)      { v2 = v1; i2 = i1; v1 = p; i1 = e; }
        else if (p > v2) { v2 = p; i2 = e; }
    }

    float* dst = out_w + (size_t)t * NEXP;
#pragma unroll
    for (int e = 0; e < NEXP; e += 4) {
        float4 o;
        o.x = (e+0 == i1) ? v1 : (e+0 == i2) ? v2 : 0.0f;
        o.y = (e+1 == i1) ? v1 : (e+1 == i2) ? v2 : 0.0f;
        o.z = (e+2 == i1) ? v1 : (e+2 == i2) ? v2 : 0.0f;
        o.w = (e+3 == i1) ? v1 : (e+3 == i2) ? v2 : 0.0f;
        *reinterpret_cast<float4*>(dst + e) = o;
    }
    out_i[(size_t)t * 2 + 0] = (float)i1;
    out_i[(size_t)t * 2 + 1] = (float)i2;
}

extern "C" void kernel_launch(void* const* d_in, const int* in_sizes, int n_in,
                              void* d_out, int out_size, void* d_ws, size_t ws_size,
                              hipStream_t stream) {
    const float* x = (const float*)d_in[0];
    const float* W = (const float*)d_in[1];
    float* out_w = (float*)d_out;
    float* out_i = out_w + (size_t)TOKENS * NEXP;

    float* part = (float*)d_ws;   // KB * 8192 * 64 f32 = 4 MB

    tg_main <<<dim3(TOKENS / TBLK * KB), dim3(512), 0, stream>>>(x, W, part);
    tg_final<<<dim3(TOKENS / 256), dim3(256), 0, stream>>>(part, out_w, out_i);
}